// Round 15
// baseline (312.237 us; speedup 1.0000x reference)
//
#include <hip/hip_runtime.h>
#include <math.h>

#define BB 16
#define NN 4096
#define MM 1024
#define KNN 32
#define R2 0.04f
#define EPSV 1e-5f
#define S1f ((float)(BB * MM * KNN))
#define S3f ((float)(BB * MM))

typedef __attribute__((ext_vector_type(8))) short short8;
typedef __attribute__((ext_vector_type(4))) short short4v;
typedef __attribute__((ext_vector_type(4))) float f32x4;

__device__ __forceinline__ short f2b(float x) {
    union { float f; unsigned u; } v; v.f = x;
    unsigned r = v.u + 0x7fffu + ((v.u >> 16) & 1u);
    return (short)(r >> 16);
}
__device__ __forceinline__ float b2f(short s) {
    union { unsigned u; float f; } v; v.u = ((unsigned)(unsigned short)s) << 16;
    return v.f;
}
// fast tanh-gelu: 0.5x(1+tanh u) == x * (1 - 1/(e^{2u}+1))
__device__ __forceinline__ float gelu_t(float x) {
    float u = 0.7978845608f * x * (1.f + 0.044715f * x * x);
    float e = __expf(2.f * u);
    float r = __builtin_amdgcn_rcpf(e + 1.f);
    return x - x * r;
}
__device__ __forceinline__ float gelu_e(float x) {  // exact (final output)
    return 0.5f * x * (1.f + erff(x * 0.7071067811865475f));
}
__device__ __forceinline__ f32x4 zero4() { f32x4 z = {0.f, 0.f, 0.f, 0.f}; return z; }
__device__ __forceinline__ f32x4 mfma(short8 a, short8 b, f32x4 c) {
    return __builtin_amdgcn_mfma_f32_16x16x32_bf16(a, b, c, 0, 0, 0);
}
__device__ __forceinline__ short8 pack8(f32x4 a, f32x4 b) {
    short8 r;
    r[0] = f2b(a[0]); r[1] = f2b(a[1]); r[2] = f2b(a[2]); r[3] = f2b(a[3]);
    r[4] = f2b(b[0]); r[5] = f2b(b[1]); r[6] = f2b(b[2]); r[7] = f2b(b[3]);
    return r;
}

// ---------------- ball query: one query per wave ----------------
__global__ __launch_bounds__(256) void k_ballquery(const float* __restrict__ src_xyz,
                                                   const float* __restrict__ xyz,
                                                   int* __restrict__ gidx) {
    __shared__ float sx[NN], sy[NN], sz[NN];
    int t = threadIdx.x;
    int lane = t & 63, w = t >> 6;
    int q0 = blockIdx.x * 16;
    int b = q0 >> 10;
    const float* sp = src_xyz + (size_t)b * NN * 3;
    for (int i = t; i < NN * 3; i += 256) {
        float v = sp[i];
        int j = i / 3, d = i - j * 3;
        if (d == 0) sx[j] = v;
        else if (d == 1) sy[j] = v;
        else sz[j] = v;
    }
    __syncthreads();
#pragma unroll
    for (int qi = 0; qi < 4; ++qi) {
        int q = q0 + w * 4 + qi;
        int m = q & 1023;
        float qx = xyz[((size_t)b * MM + m) * 3 + 0];
        float qy = xyz[((size_t)b * MM + m) * 3 + 1];
        float qz = xyz[((size_t)b * MM + m) * 3 + 2];
        int* outp = gidx + (size_t)q * KNN;
        int cnt = 0, firstj = -1;
        for (int j0 = 0; j0 < NN && cnt < KNN; j0 += 64) {
            int j = j0 + lane;
            float dx = qx - sx[j];
            float dy = qy - sy[j];
            float dz = qz - sz[j];
            bool hit = (dx * dx + dy * dy + dz * dz) <= R2;
            unsigned long long mask = __ballot(hit);
            if (hit) {
                int rank = cnt + __popcll(mask & ((1ull << lane) - 1ull));
                if (rank < KNN) outp[rank] = j;
            }
            if (firstj < 0 && mask != 0ull) firstj = j0 + __ffsll((long long)mask) - 1;
            cnt += __popcll(mask);
        }
        if (cnt < KNN) {
            int fj = (firstj < 0) ? 0 : firstj;
            for (int k = cnt + lane; k < KNN; k += 64) outp[k] = fj;
        }
    }
}

// ---------------- prep: src_x -> bf16; weights -> bf16; w3 lane-major frag repack ----------------
__global__ __launch_bounds__(256) void k_prep(const float* __restrict__ src_x,
                                              const float* __restrict__ w1,
                                              const float* __restrict__ w2,
                                              const float* __restrict__ w3,
                                              short* __restrict__ src_xb,
                                              short* __restrict__ w1b,
                                              short* __restrict__ w2b,
                                              short* __restrict__ w3b,
                                              short* __restrict__ w3p) {
    int i = blockIdx.x * 256 + threadIdx.x;
    if (i < 524288) {  // BB*NN*64/8
        const f32x4* p = (const f32x4*)(src_x + (size_t)i * 8);
        *(short8*)(src_xb + (size_t)i * 8) = pack8(p[0], p[1]);
    } else {
        int j = i - 524288;
        if (j < 6144) {
            int n = j / 96, k = j % 96;
            float v = 0.f;
            if (k < 64) v = w1[n * 67 + 3 + k];
            else if (k < 67) v = w1[n * 67 + (k - 64)];
            w1b[j] = f2b(v);
        } else if (j < 14336) {
            w2b[j - 6144] = f2b(w2[j - 6144]);
        } else if (j < 47104) {
            w3b[j - 14336] = f2b(w3[j - 14336]);
        } else if (j < 79872) {
            int j2 = j - 47104;            // [0, 32768)
            int e = j2 & 7;
            int lane = (j2 >> 3) & 63;
            int idx = j2 >> 9;             // (nc*4+kf)*4+nf
            int nf = idx & 3, kf = (idx >> 2) & 3, nc = idx >> 4;
            int ln = lane & 15, qq = lane >> 4;
            w3p[j2] = f2b(w3[(size_t)(nc * 64 + nf * 16 + ln) * 128 + kf * 32 + qq * 8 + e]);
        }
    }
}

// Per-wave gather into wave-private region R (feat rows stride 72, 16B-aligned).
#define GATHER_WAVE(R)                                                                  \
    {                                                                                   \
        if (lane < 8) { short4v z4 = {0, 0, 0, 0};                                      \
            *(short4v*)((R) + 2304 + lane * 4) = z4; }                                  \
        int r = lane >> 1, hf = lane & 1;                                               \
        int jdx = gidx[(size_t)g * KNN + r];                                            \
        const short8* sp = (const short8*)(src_xb + ((size_t)b * NN + jdx) * 64 + hf * 32); \
        *(short8*)((R) + r * 72 + hf * 32) = sp[0];                                     \
        *(short8*)((R) + r * 72 + hf * 32 + 8) = sp[1];                                 \
        *(short8*)((R) + r * 72 + hf * 32 + 16) = sp[2];                                \
        *(short8*)((R) + r * 72 + hf * 32 + 24) = sp[3];                                \
        if (hf == 0) {                                                                  \
            const float* spp = src_xyz + ((size_t)b * NN + jdx) * 3;                    \
            short4v z;                                                                  \
            z[0] = f2b(spp[0] - qx); z[1] = f2b(spp[1] - qy);                           \
            z[2] = f2b(spp[2] - qz); z[3] = 0;                                          \
            *(short4v*)((R) + r * 72 + 64) = z;                                         \
            short4v z0 = {0, 0, 0, 0};                                                  \
            *(short4v*)((R) + r * 72 + 68) = z0;                                        \
        }                                                                               \
    }

// Build BN1 scale/shift into sc1L/sh1L (threads t<64)
#define BN1_SCALES                                                                      \
    if (t < 64) {                                                                       \
        float s = 0.f, sq = 0.f;                                                        \
        _Pragma("unroll")                                                               \
        for (int r = 0; r < 8; ++r) { s += stats1[r * 128 + t]; sq += stats1[r * 128 + 64 + t]; } \
        float mu = s * (1.f / S1f);                                                     \
        float var = sq * (1.f / S1f) - mu * mu;                                         \
        float rs = rsqrtf(var + EPSV);                                                  \
        float sc = g1[t] * rs;                                                          \
        sc1L[t] = sc;                                                                   \
        sh1L[t] = b1[t] - mu * sc;                                                      \
    }

// L1 swapped (W1 = A): acc1[sf][nf]: D rows=ch nf*16+qq*4+jj, cols=sample sf*16+ln
#define L1_SWAPPED(R, acc1)                                                             \
    short8 bAct[2][3];                                                                  \
    _Pragma("unroll")                                                                   \
    for (int sf = 0; sf < 2; ++sf)                                                      \
        _Pragma("unroll")                                                               \
        for (int kf = 0; kf < 3; ++kf)                                                  \
            bAct[sf][kf] = *(const short8*)((R) + (sf * 16 + ln) * 72 + kf * 32 + qq * 8); \
    _Pragma("unroll")                                                                   \
    for (int sf = 0; sf < 2; ++sf)                                                      \
        _Pragma("unroll")                                                               \
        for (int nf = 0; nf < 4; ++nf) acc1[sf][nf] = zero4();                          \
    _Pragma("unroll")                                                                   \
    for (int kf = 0; kf < 3; ++kf)                                                      \
        _Pragma("unroll")                                                               \
        for (int nf = 0; nf < 4; ++nf) {                                                \
            short8 aW = *(const short8*)(w1b + (nf * 16 + ln) * 96 + kf * 32 + qq * 8); \
            acc1[0][nf] = mfma(aW, bAct[0][kf], acc1[0][nf]);                           \
            acc1[1][nf] = mfma(aW, bAct[1][kf], acc1[1][nf]);                           \
        }

// Decode packed pre-h1 -> BN1 + fast gelu -> [sample][ch] tile R (stride 72), b64 writes.
#define H1_DECODE(R, hv)                                                                \
    _Pragma("unroll")                                                                   \
    for (int i = 0; i < 4; ++i) {                                                       \
        int sf_ = i >> 1, pr_ = i & 1;                                                  \
        _Pragma("unroll")                                                               \
        for (int hh = 0; hh < 2; ++hh) {                                                \
            int c0_ = (2 * pr_ + hh) * 16 + qq * 4;                                     \
            f32x4 sc = *(const f32x4*)(sc1L + c0_);                                     \
            f32x4 sh = *(const f32x4*)(sh1L + c0_);                                     \
            short4v sv;                                                                 \
            _Pragma("unroll")                                                           \
            for (int jj = 0; jj < 4; ++jj)                                              \
                sv[jj] = f2b(gelu_t(b2f(hv[i][hh * 4 + jj]) * sc[jj] + sh[jj]));        \
            *(short4v*)((R) + (sf_ * 16 + ln) * 72 + c0_) = sv;                         \
        }                                                                               \
    }

// Swapped L2 from [sample][ch] tile + pack-store + stats2 (shared tail for both s2 variants)
#define L2_TAIL(R)                                                                      \
    short8 bh1[2][2];                                                                   \
    _Pragma("unroll")                                                                   \
    for (int sf = 0; sf < 2; ++sf)                                                      \
        _Pragma("unroll")                                                               \
        for (int kf = 0; kf < 2; ++kf)                                                  \
            bh1[sf][kf] = *(const short8*)((R) + (sf * 16 + ln) * 72 + kf * 32 + qq * 8); \
    f32x4 acc2[2][8];                                                                   \
    _Pragma("unroll")                                                                   \
    for (int sf = 0; sf < 2; ++sf)                                                      \
        _Pragma("unroll")                                                               \
        for (int nf = 0; nf < 8; ++nf) acc2[sf][nf] = zero4();                          \
    _Pragma("unroll")                                                                   \
    for (int kf = 0; kf < 2; ++kf)                                                      \
        _Pragma("unroll")                                                               \
        for (int nf = 0; nf < 8; ++nf) {                                                \
            short8 aW = *(const short8*)(w2b + (nf * 16 + ln) * 64 + kf * 32 + qq * 8); \
            acc2[0][nf] = mfma(aW, bh1[0][kf], acc2[0][nf]);                            \
            acc2[1][nf] = mfma(aW, bh1[1][kf], acc2[1][nf]);                            \
        }                                                                               \
    {                                                                                   \
        short* hb2 = h2p + (size_t)g * 4096;                                            \
        _Pragma("unroll")                                                               \
        for (int i = 0; i < 8; ++i) {                                                   \
            int sf = i >> 2, p = i & 3;                                                 \
            *(short8*)(hb2 + (i * 64 + lane) * 8) = pack8(acc2[sf][2 * p], acc2[sf][2 * p + 1]); \
        }                                                                               \
    }                                                                                   \
    _Pragma("unroll")                                                                   \
    for (int nf = 0; nf < 8; ++nf) {                                                    \
        f32x4 s, q;                                                                     \
        _Pragma("unroll")                                                               \
        for (int jj = 0; jj < 4; ++jj) {                                                \
            float a0 = acc2[0][nf][jj], a1 = acc2[1][nf][jj];                           \
            s[jj] = a0 + a1; q[jj] = a0 * a0 + a1 * a1;                                 \
        }                                                                               \
        _Pragma("unroll")                                                               \
        for (int d = 1; d < 16; d <<= 1) {                                              \
            _Pragma("unroll")                                                           \
            for (int jj = 0; jj < 4; ++jj) {                                            \
                s[jj] += __shfl_xor(s[jj], d);                                          \
                q[jj] += __shfl_xor(q[jj], d);                                          \
            }                                                                           \
        }                                                                               \
        if (ln == 0) {                                                                  \
            *(f32x4*)(redS + w * 128 + nf * 16 + qq * 4) = s;                           \
            *(f32x4*)(redQ + w * 128 + nf * 16 + qq * 4) = q;                           \
        }                                                                               \
    }                                                                                   \
    __syncthreads();                                                                    \
    if (t < 128) {                                                                      \
        float s = redS[t] + redS[128 + t] + redS[256 + t] + redS[384 + t];              \
        float q = redQ[t] + redQ[128 + t] + redQ[256 + t] + redQ[384 + t];              \
        float* st = stats2 + (blockIdx.x & 7) * 256;                                    \
        atomicAdd(&st[t], s);                                                           \
        atomicAdd(&st[128 + t], q);                                                     \
    }

// ---------------- s1: gather + L1 (swapped) + stats1 (+ optional packed pre-h1 store) ----------------
__global__ __launch_bounds__(256, 6) void k_s1(const int* __restrict__ gidx,
                                               const float* __restrict__ src_xyz,
                                               const float* __restrict__ xyz,
                                               const short* __restrict__ src_xb,
                                               const short* __restrict__ w1b,
                                               float* __restrict__ stats1,
                                               short* __restrict__ h1p) {
    __shared__ short wbuf[4][2336];
    __shared__ float redS[256], redQ[256];
    int t = threadIdx.x, lane = t & 63, w = t >> 6, ln = lane & 15, qq = lane >> 4;
    int g = blockIdx.x * 4 + w, b = g >> 10, m = g & 1023;
    float qx = xyz[((size_t)b * MM + m) * 3 + 0];
    float qy = xyz[((size_t)b * MM + m) * 3 + 1];
    float qz = xyz[((size_t)b * MM + m) * 3 + 2];
    short* R = wbuf[w];
    GATHER_WAVE(R)
    f32x4 acc1[2][4];
    L1_SWAPPED(R, acc1)
    if (h1p) {  // packed lane-major store: 4 x b128, 1KB contiguous per wave-instruction
        short* hb = h1p + (size_t)g * 2048;
#pragma unroll
        for (int i = 0; i < 4; ++i) {
            int sf = i >> 1, p = i & 1;
            *(short8*)(hb + (i * 64 + lane) * 8) = pack8(acc1[sf][2 * p], acc1[sf][2 * p + 1]);
        }
    }
#pragma unroll
    for (int nf = 0; nf < 4; ++nf) {
        f32x4 s, q;
#pragma unroll
        for (int jj = 0; jj < 4; ++jj) {
            float a0 = acc1[0][nf][jj], a1 = acc1[1][nf][jj];
            s[jj] = a0 + a1; q[jj] = a0 * a0 + a1 * a1;
        }
#pragma unroll
        for (int d = 1; d < 16; d <<= 1) {
#pragma unroll
            for (int jj = 0; jj < 4; ++jj) {
                s[jj] += __shfl_xor(s[jj], d);
                q[jj] += __shfl_xor(q[jj], d);
            }
        }
        if (ln == 0) {
            *(f32x4*)(redS + w * 64 + nf * 16 + qq * 4) = s;
            *(f32x4*)(redQ + w * 64 + nf * 16 + qq * 4) = q;
        }
    }
    __syncthreads();
    if (t < 64) {
        float s = redS[t] + redS[64 + t] + redS[128 + t] + redS[192 + t];
        float q = redQ[t] + redQ[64 + t] + redQ[128 + t] + redQ[192 + t];
        float* st = stats1 + (blockIdx.x & 7) * 128;
        atomicAdd(&st[t], s);
        atomicAdd(&st[64 + t], q);
    }
}

// ---------------- s2 fast: coalesced h1p read -> decode -> L2 tail (no gather, no L1) ----------------
__global__ __launch_bounds__(256, 6) void k_s2f(const short* __restrict__ h1p,
                                                const short* __restrict__ w2b,
                                                const float* __restrict__ g1,
                                                const float* __restrict__ b1,
                                                const float* __restrict__ stats1,
                                                float* __restrict__ stats2,
                                                short* __restrict__ h2p) {
    __shared__ short wbuf[4][2336];
    __shared__ float sc1L[64], sh1L[64];
    __shared__ float redS[512], redQ[512];
    int t = threadIdx.x, lane = t & 63, w = t >> 6, ln = lane & 15, qq = lane >> 4;
    int g = blockIdx.x * 4 + w;
    const short* hb = h1p + (size_t)g * 2048;
    short8 hv[4];
#pragma unroll
    for (int i = 0; i < 4; ++i) hv[i] = *(const short8*)(hb + (i * 64 + lane) * 8);
    BN1_SCALES
    __syncthreads();  // sc1L ready
    short* R = wbuf[w];
    H1_DECODE(R, hv)
    L2_TAIL(R)
}

// ---------------- s2 slow (fallback, r14-proven): gather + L1 + decode-in-reg + L2 tail ----------------
__global__ __launch_bounds__(256, 4) void k_s2(const int* __restrict__ gidx,
                                               const float* __restrict__ src_xyz,
                                               const float* __restrict__ xyz,
                                               const short* __restrict__ src_xb,
                                               const short* __restrict__ w1b,
                                               const short* __restrict__ w2b,
                                               const float* __restrict__ g1,
                                               const float* __restrict__ b1,
                                               const float* __restrict__ stats1,
                                               float* __restrict__ stats2,
                                               short* __restrict__ h2p) {
    __shared__ short wbuf[4][2336];
    __shared__ float sc1L[64], sh1L[64];
    __shared__ float redS[512], redQ[512];
    int t = threadIdx.x, lane = t & 63, w = t >> 6, ln = lane & 15, qq = lane >> 4;
    int g = blockIdx.x * 4 + w, b = g >> 10, m = g & 1023;
    float qx = xyz[((size_t)b * MM + m) * 3 + 0];
    float qy = xyz[((size_t)b * MM + m) * 3 + 1];
    float qz = xyz[((size_t)b * MM + m) * 3 + 2];
    short* R = wbuf[w];
    GATHER_WAVE(R)
    BN1_SCALES
    f32x4 acc1[2][4];
    L1_SWAPPED(R, acc1)
    __syncthreads();  // sc1L ready (feat already consumed into bAct)
#pragma unroll
    for (int sf = 0; sf < 2; ++sf)
#pragma unroll
        for (int nf = 0; nf < 4; ++nf) {
            int c0 = nf * 16 + qq * 4;
            f32x4 sc = *(const f32x4*)(sc1L + c0);
            f32x4 sh = *(const f32x4*)(sh1L + c0);
            short4v sv;
#pragma unroll
            for (int jj = 0; jj < 4; ++jj)
                sv[jj] = f2b(gelu_t(acc1[sf][nf][jj] * sc[jj] + sh[jj]));
            *(short4v*)(R + (sf * 16 + ln) * 72 + c0) = sv;
        }
    L2_TAIL(R)
}

// ---------------- k3: packed pre-h2 read -> BN2+gelu -> LDS -> L3 (w3p) + max + fused stats3 ----------------
__global__ __launch_bounds__(256, 4) void k3(const short* __restrict__ h2p,
                                             const short* __restrict__ w3p,
                                             const float* __restrict__ g2,
                                             const float* __restrict__ b2,
                                             const float* __restrict__ stats2,
                                             float* __restrict__ stats3,
                                             float* __restrict__ out) {
    __shared__ short wbuf[4][4352];   // per-wave [32 sample][136] h2 tile
    __shared__ float sc2L[128], sh2L[128];
    __shared__ float mxS[4][256];     // per-wave channel max (for fused stats3)
    int t = threadIdx.x, lane = t & 63, w = t >> 6, ln = lane & 15, qq = lane >> 4;
    int g = blockIdx.x * 4 + w;
    const short* hb = h2p + (size_t)g * 4096;
    short8 hv[8];
#pragma unroll
    for (int i = 0; i < 8; ++i) hv[i] = *(const short8*)(hb + (i * 64 + lane) * 8);
    if (t < 128) {
        float s = 0.f, sq = 0.f;
#pragma unroll
        for (int r = 0; r < 8; ++r) { s += stats2[r * 256 + t]; sq += stats2[r * 256 + 128 + t]; }
        float mu = s * (1.f / S1f);
        float var = sq * (1.f / S1f) - mu * mu;
        float rs = rsqrtf(var + EPSV);
        float sc = g2[t] * rs;
        sc2L[t] = sc;
        sh2L[t] = b2[t] - mu * sc;
    }
    __syncthreads();  // scales ready
    short* R = wbuf[w];
#pragma unroll
    for (int i = 0; i < 8; ++i) {
        int sf = i >> 2, p = i & 3;
#pragma unroll
        for (int hh = 0; hh < 2; ++hh) {
            int c0 = (2 * p + hh) * 16 + qq * 4;
            f32x4 sc = *(const f32x4*)(sc2L + c0);
            f32x4 sh = *(const f32x4*)(sh2L + c0);
            short4v sv;
#pragma unroll
            for (int jj = 0; jj < 4; ++jj)
                sv[jj] = f2b(gelu_t(b2f(hv[i][hh * 4 + jj]) * sc[jj] + sh[jj]));
            *(short4v*)(R + (sf * 16 + ln) * 136 + c0) = sv;
        }
    }
    short8 b3[2][4];
#pragma unroll
    for (int sf = 0; sf < 2; ++sf)
#pragma unroll
        for (int kf = 0; kf < 4; ++kf)
            b3[sf][kf] = *(const short8*)(R + (sf * 16 + ln) * 136 + kf * 32 + qq * 8);
#pragma unroll
    for (int nc = 0; nc < 4; ++nc) {
        f32x4 acc3[2][4];
#pragma unroll
        for (int sf = 0; sf < 2; ++sf)
#pragma unroll
            for (int nf = 0; nf < 4; ++nf) acc3[sf][nf] = zero4();
#pragma unroll
        for (int kf = 0; kf < 4; ++kf)
#pragma unroll
            for (int nf = 0; nf < 4; ++nf) {
                short8 aW = *(const short8*)(w3p + (((nc * 4 + kf) * 4 + nf) * 64 + lane) * 8);
                acc3[0][nf] = mfma(aW, b3[0][kf], acc3[0][nf]);
                acc3[1][nf] = mfma(aW, b3[1][kf], acc3[1][nf]);
            }
#pragma unroll
        for (int nf = 0; nf < 4; ++nf) {
            f32x4 v;
#pragma unroll
            for (int jj = 0; jj < 4; ++jj) v[jj] = fmaxf(acc3[0][nf][jj], acc3[1][nf][jj]);
#pragma unroll
            for (int d = 1; d < 16; d <<= 1) {
#pragma unroll
                for (int jj = 0; jj < 4; ++jj) v[jj] = fmaxf(v[jj], __shfl_xor(v[jj], d));
            }
            if (ln == 0) {
                *(f32x4*)(out + (size_t)g * 256 + nc * 64 + nf * 16 + qq * 4) = v;
                *(f32x4*)(&mxS[w][nc * 64 + nf * 16 + qq * 4]) = v;
            }
        }
    }
    __syncthreads();  // mxS complete
    if (t < 256) {
        float a0 = mxS[0][t], a1 = mxS[1][t], a2 = mxS[2][t], a3 = mxS[3][t];
        float s = a0 + a1 + a2 + a3;
        float q = a0 * a0 + a1 * a1 + a2 * a2 + a3 * a3;
        float* st = stats3 + (blockIdx.x & 7) * 512;
        atomicAdd(&st[t], s);
        atomicAdd(&st[256 + t], q);
    }
}

// ---------------- final BN + exact GELU (reads 8-replicated stats3) ----------------
__global__ __launch_bounds__(256) void k_bn3(float* __restrict__ out,
                                             const float* __restrict__ stats3,
                                             const float* __restrict__ gl,
                                             const float* __restrict__ bl) {
    int i = blockIdx.x * 256 + threadIdx.x;
    int o = i & 255;
    float s = 0.f, q = 0.f;
#pragma unroll
    for (int r = 0; r < 8; ++r) { s += stats3[r * 512 + o]; q += stats3[r * 512 + 256 + o]; }
    float mu = s * (1.f / S3f);
    float var = q * (1.f / S3f) - mu * mu;
    float rs = rsqrtf(var + EPSV);
    float x = out[i];
    out[i] = gelu_e((x - mu) * rs * gl[o] + bl[o]);
}

extern "C" void kernel_launch(void* const* d_in, const int* in_sizes, int n_in,
                              void* d_out, int out_size, void* d_ws, size_t ws_size,
                              hipStream_t stream) {
    const float* src_x   = (const float*)d_in[0];
    const float* src_xyz = (const float*)d_in[1];
    const float* xyz     = (const float*)d_in[2];
    const float* w1      = (const float*)d_in[3];
    const float* g1      = (const float*)d_in[4];
    const float* b1      = (const float*)d_in[5];
    const float* w2      = (const float*)d_in[6];
    const float* g2      = (const float*)d_in[7];
    const float* b2      = (const float*)d_in[8];
    const float* w3      = (const float*)d_in[9];
    const float* gl      = (const float*)d_in[10];
    const float* bl      = (const float*)d_in[11];
    float* out = (float*)d_out;

    int* gidx = (int*)d_ws;                              // 2 MB
    float* statsF = (float*)(gidx + BB * MM * KNN);
    float* stats1 = statsF;          // 8 x (64 sum | 64 sq)   = 1024
    float* stats2 = statsF + 1024;   // 8 x (128 sum | 128 sq) = 2048
    float* stats3 = statsF + 3072;   // 8 x (256 sum | 256 sq) = 4096
    short* wb = (short*)(statsF + 7168);
    short* w1b = wb;                 // [64][96] reordered
    short* w2b = wb + 6144;          // [128][64]
    short* w3b = wb + 14336;         // [256][128] row-major
    short* w3p = wb + 47104;         // [4][4][4][64][8] lane-major frag pack (64 KB)
    short* src_xb = wb + 79872;      // [B][N][64] bf16 (ends ~10.7 MB)
    // big path: h1p 64 MB @16MB, h2p 128 MB @80MB -> NEED 208 MB (ws>=144MB proven; branch)
    short* h1p = (short*)((char*)d_ws + (size_t)(16u << 20));
    const size_t NEED_BIG = (size_t)(208u) << 20;
    bool big = ws_size >= NEED_BIG;
    short* h2p = big ? (short*)((char*)d_ws + ((size_t)(80u) << 20))
                     : (short*)((char*)d_ws + ((size_t)(16u) << 20));

    hipMemsetAsync(statsF, 0, 7168 * sizeof(float), stream);
    k_prep<<<2360, 256, 0, stream>>>(src_x, w1, w2, w3, src_xb, w1b, w2b, w3b, w3p);
    k_ballquery<<<(BB * MM) / 16, 256, 0, stream>>>(src_xyz, xyz, gidx);
    k_s1<<<(BB * MM) / 4, 256, 0, stream>>>(gidx, src_xyz, xyz, src_xb, w1b, stats1,
                                            big ? h1p : (short*)nullptr);
    if (big) {
        k_s2f<<<(BB * MM) / 4, 256, 0, stream>>>(h1p, w2b, g1, b1, stats1, stats2, h2p);
    } else {
        k_s2<<<(BB * MM) / 4, 256, 0, stream>>>(gidx, src_xyz, xyz, src_xb, w1b, w2b, g1, b1,
                                                stats1, stats2, h2p);
    }
    k3<<<(BB * MM) / 4, 256, 0, stream>>>(h2p, w3p, g2, b2, stats2, stats3, out);
    k_bn3<<<BB * MM, 256, 0, stream>>>(out, stats3, gl, bl);
}

// Round 16
// 260.076 us; speedup vs baseline: 1.2006x; 1.2006x over previous
//
#include <hip/hip_runtime.h>
#include <math.h>

#define BB 16
#define NN 4096
#define MM 1024
#define KNN 32
#define R2 0.04f
#define EPSV 1e-5f
#define S1f ((float)(BB * MM * KNN))
#define S3f ((float)(BB * MM))

typedef __attribute__((ext_vector_type(8))) short short8;
typedef __attribute__((ext_vector_type(4))) short short4v;
typedef __attribute__((ext_vector_type(4))) float f32x4;

__device__ __forceinline__ short f2b(float x) {
    union { float f; unsigned u; } v; v.f = x;
    unsigned r = v.u + 0x7fffu + ((v.u >> 16) & 1u);
    return (short)(r >> 16);
}
__device__ __forceinline__ float b2f(short s) {
    union { unsigned u; float f; } v; v.u = ((unsigned)(unsigned short)s) << 16;
    return v.f;
}
// fast tanh-gelu: 0.5x(1+tanh u) == x * (1 - 1/(e^{2u}+1))
__device__ __forceinline__ float gelu_t(float x) {
    float u = 0.7978845608f * x * (1.f + 0.044715f * x * x);
    float e = __expf(2.f * u);
    float r = __builtin_amdgcn_rcpf(e + 1.f);
    return x - x * r;
}
__device__ __forceinline__ float gelu_e(float x) {  // exact (final output)
    return 0.5f * x * (1.f + erff(x * 0.7071067811865475f));
}
__device__ __forceinline__ f32x4 zero4() { f32x4 z = {0.f, 0.f, 0.f, 0.f}; return z; }
__device__ __forceinline__ f32x4 mfma(short8 a, short8 b, f32x4 c) {
    return __builtin_amdgcn_mfma_f32_16x16x32_bf16(a, b, c, 0, 0, 0);
}
__device__ __forceinline__ short8 pack8(f32x4 a, f32x4 b) {
    short8 r;
    r[0] = f2b(a[0]); r[1] = f2b(a[1]); r[2] = f2b(a[2]); r[3] = f2b(a[3]);
    r[4] = f2b(b[0]); r[5] = f2b(b[1]); r[6] = f2b(b[2]); r[7] = f2b(b[3]);
    return r;
}

// ---------------- ball query: one query per wave ----------------
__global__ __launch_bounds__(256) void k_ballquery(const float* __restrict__ src_xyz,
                                                   const float* __restrict__ xyz,
                                                   int* __restrict__ gidx) {
    __shared__ float sx[NN], sy[NN], sz[NN];
    int t = threadIdx.x;
    int lane = t & 63, w = t >> 6;
    int q0 = blockIdx.x * 16;
    int b = q0 >> 10;
    const float* sp = src_xyz + (size_t)b * NN * 3;
    for (int i = t; i < NN * 3; i += 256) {
        float v = sp[i];
        int j = i / 3, d = i - j * 3;
        if (d == 0) sx[j] = v;
        else if (d == 1) sy[j] = v;
        else sz[j] = v;
    }
    __syncthreads();
#pragma unroll
    for (int qi = 0; qi < 4; ++qi) {
        int q = q0 + w * 4 + qi;
        int m = q & 1023;
        float qx = xyz[((size_t)b * MM + m) * 3 + 0];
        float qy = xyz[((size_t)b * MM + m) * 3 + 1];
        float qz = xyz[((size_t)b * MM + m) * 3 + 2];
        int* outp = gidx + (size_t)q * KNN;
        int cnt = 0, firstj = -1;
        for (int j0 = 0; j0 < NN && cnt < KNN; j0 += 64) {
            int j = j0 + lane;
            float dx = qx - sx[j];
            float dy = qy - sy[j];
            float dz = qz - sz[j];
            bool hit = (dx * dx + dy * dy + dz * dz) <= R2;
            unsigned long long mask = __ballot(hit);
            if (hit) {
                int rank = cnt + __popcll(mask & ((1ull << lane) - 1ull));
                if (rank < KNN) outp[rank] = j;
            }
            if (firstj < 0 && mask != 0ull) firstj = j0 + __ffsll((long long)mask) - 1;
            cnt += __popcll(mask);
        }
        if (cnt < KNN) {
            int fj = (firstj < 0) ? 0 : firstj;
            for (int k = cnt + lane; k < KNN; k += 64) outp[k] = fj;
        }
    }
}

// ---------------- prep: src_x -> bf16; w1/w2/w3 -> lane-major MFMA fragment packs ----------------
// All weight fragments stored so the wave's A-operand load is ONE coalesced 1KB b128 read:
//   wp[(frag)*512 + lane*8 + e]  with  row = nf*16 + (lane&15), col = kf*32 + (lane>>4)*8 + e
// w1 frag cols use the reordered K: 0..63 = orig cols 3..66 (src_x), 64..66 = orig 0..2 (cxyz), 67..95 = 0
__global__ __launch_bounds__(256) void k_prep(const float* __restrict__ src_x,
                                              const float* __restrict__ w1,
                                              const float* __restrict__ w2,
                                              const float* __restrict__ w3,
                                              short* __restrict__ src_xb,
                                              short* __restrict__ w1p,
                                              short* __restrict__ w2p,
                                              short* __restrict__ w3p) {
    int i = blockIdx.x * 256 + threadIdx.x;
    if (i < 524288) {  // BB*NN*64/8
        const f32x4* p = (const f32x4*)(src_x + (size_t)i * 8);
        *(short8*)(src_xb + (size_t)i * 8) = pack8(p[0], p[1]);
    } else {
        int j = i - 524288;
        if (j < 6144) {            // w1p: 12 frags (kf 0..2, nf 0..3)
            int e = j & 7, lane = (j >> 3) & 63, idx = j >> 9;
            int kf = idx >> 2, nf = idx & 3;
            int ln = lane & 15, qq = lane >> 4;
            int n = nf * 16 + ln, k = kf * 32 + qq * 8 + e;
            float v = 0.f;
            if (k < 64) v = w1[n * 67 + 3 + k];
            else if (k < 67) v = w1[n * 67 + (k - 64)];
            w1p[j] = f2b(v);
        } else if (j < 14336) {    // w2p: 16 frags (kf 0..1, nf 0..7)
            int j2 = j - 6144;
            int e = j2 & 7, lane = (j2 >> 3) & 63, idx = j2 >> 9;
            int kf = idx >> 3, nf = idx & 7;
            int ln = lane & 15, qq = lane >> 4;
            w2p[j2] = f2b(w2[(nf * 16 + ln) * 64 + kf * 32 + qq * 8 + e]);
        } else if (j < 47104) {    // w3p: 64 frags (nc 0..3, kf 0..3, nf 0..3)
            int j2 = j - 14336;
            int e = j2 & 7, lane = (j2 >> 3) & 63, idx = j2 >> 9;
            int nf = idx & 3, kf = (idx >> 2) & 3, nc = idx >> 4;
            int ln = lane & 15, qq = lane >> 4;
            w3p[j2] = f2b(w3[(size_t)(nc * 64 + nf * 16 + ln) * 128 + kf * 32 + qq * 8 + e]);
        }
    }
}

// Per-wave gather into wave-private region R (feat rows stride 72, 16B-aligned).
#define GATHER_WAVE(R)                                                                  \
    {                                                                                   \
        if (lane < 8) { short4v z4 = {0, 0, 0, 0};                                      \
            *(short4v*)((R) + 2304 + lane * 4) = z4; }                                  \
        int r = lane >> 1, hf = lane & 1;                                               \
        int jdx = gidx[(size_t)g * KNN + r];                                            \
        const short8* sp = (const short8*)(src_xb + ((size_t)b * NN + jdx) * 64 + hf * 32); \
        *(short8*)((R) + r * 72 + hf * 32) = sp[0];                                     \
        *(short8*)((R) + r * 72 + hf * 32 + 8) = sp[1];                                 \
        *(short8*)((R) + r * 72 + hf * 32 + 16) = sp[2];                                \
        *(short8*)((R) + r * 72 + hf * 32 + 24) = sp[3];                                \
        if (hf == 0) {                                                                  \
            const float* spp = src_xyz + ((size_t)b * NN + jdx) * 3;                    \
            short4v z;                                                                  \
            z[0] = f2b(spp[0] - qx); z[1] = f2b(spp[1] - qy);                           \
            z[2] = f2b(spp[2] - qz); z[3] = 0;                                          \
            *(short4v*)((R) + r * 72 + 64) = z;                                         \
            short4v z0 = {0, 0, 0, 0};                                                  \
            *(short4v*)((R) + r * 72 + 68) = z0;                                        \
        }                                                                               \
    }

// Build BN1 scale/shift into sc1L/sh1L (threads t<64)
#define BN1_SCALES                                                                      \
    if (t < 64) {                                                                       \
        float s = 0.f, sq = 0.f;                                                        \
        _Pragma("unroll")                                                               \
        for (int r = 0; r < 8; ++r) { s += stats1[r * 128 + t]; sq += stats1[r * 128 + 64 + t]; } \
        float mu = s * (1.f / S1f);                                                     \
        float var = sq * (1.f / S1f) - mu * mu;                                         \
        float rs = rsqrtf(var + EPSV);                                                  \
        float sc = g1[t] * rs;                                                          \
        sc1L[t] = sc;                                                                   \
        sh1L[t] = b1[t] - mu * sc;                                                      \
    }

// L1 swapped (W1 = A from lane-major pack): acc1[sf][nf]: D rows=ch nf*16+qq*4+jj, cols=sample sf*16+ln
#define L1_SWAPPED(R, acc1)                                                             \
    short8 bAct[2][3];                                                                  \
    _Pragma("unroll")                                                                   \
    for (int sf = 0; sf < 2; ++sf)                                                      \
        _Pragma("unroll")                                                               \
        for (int kf = 0; kf < 3; ++kf)                                                  \
            bAct[sf][kf] = *(const short8*)((R) + (sf * 16 + ln) * 72 + kf * 32 + qq * 8); \
    _Pragma("unroll")                                                                   \
    for (int sf = 0; sf < 2; ++sf)                                                      \
        _Pragma("unroll")                                                               \
        for (int nf = 0; nf < 4; ++nf) acc1[sf][nf] = zero4();                          \
    _Pragma("unroll")                                                                   \
    for (int kf = 0; kf < 3; ++kf)                                                      \
        _Pragma("unroll")                                                               \
        for (int nf = 0; nf < 4; ++nf) {                                                \
            short8 aW = *(const short8*)(w1p + (((kf * 4 + nf) * 64) + lane) * 8);      \
            acc1[0][nf] = mfma(aW, bAct[0][kf], acc1[0][nf]);                           \
            acc1[1][nf] = mfma(aW, bAct[1][kf], acc1[1][nf]);                           \
        }

// ---------------- s1: gather + L1 (swapped) + stats1 ----------------
__global__ __launch_bounds__(256, 6) void k_s1(const int* __restrict__ gidx,
                                               const float* __restrict__ src_xyz,
                                               const float* __restrict__ xyz,
                                               const short* __restrict__ src_xb,
                                               const short* __restrict__ w1p,
                                               float* __restrict__ stats1) {
    __shared__ short wbuf[4][2336];
    __shared__ float redS[256], redQ[256];
    int t = threadIdx.x, lane = t & 63, w = t >> 6, ln = lane & 15, qq = lane >> 4;
    int g = blockIdx.x * 4 + w, b = g >> 10, m = g & 1023;
    float qx = xyz[((size_t)b * MM + m) * 3 + 0];
    float qy = xyz[((size_t)b * MM + m) * 3 + 1];
    float qz = xyz[((size_t)b * MM + m) * 3 + 2];
    short* R = wbuf[w];
    GATHER_WAVE(R)
    f32x4 acc1[2][4];
    L1_SWAPPED(R, acc1)
#pragma unroll
    for (int nf = 0; nf < 4; ++nf) {
        f32x4 s, q;
#pragma unroll
        for (int jj = 0; jj < 4; ++jj) {
            float a0 = acc1[0][nf][jj], a1 = acc1[1][nf][jj];
            s[jj] = a0 + a1; q[jj] = a0 * a0 + a1 * a1;
        }
#pragma unroll
        for (int d = 1; d < 16; d <<= 1) {
#pragma unroll
            for (int jj = 0; jj < 4; ++jj) {
                s[jj] += __shfl_xor(s[jj], d);
                q[jj] += __shfl_xor(q[jj], d);
            }
        }
        if (ln == 0) {
            *(f32x4*)(redS + w * 64 + nf * 16 + qq * 4) = s;
            *(f32x4*)(redQ + w * 64 + nf * 16 + qq * 4) = q;
        }
    }
    __syncthreads();
    if (t < 64) {
        float s = redS[t] + redS[64 + t] + redS[128 + t] + redS[192 + t];
        float q = redQ[t] + redQ[64 + t] + redQ[128 + t] + redQ[192 + t];
        float* st = stats1 + (blockIdx.x & 7) * 128;
        atomicAdd(&st[t], s);
        atomicAdd(&st[64 + t], q);
    }
}

// ---------------- s2: gather + L1 + BN1/gelu + L2 (swapped, packed w2) + stats2 + h2p store ----------------
__global__ __launch_bounds__(256, 4) void k_s2(const int* __restrict__ gidx,
                                               const float* __restrict__ src_xyz,
                                               const float* __restrict__ xyz,
                                               const short* __restrict__ src_xb,
                                               const short* __restrict__ w1p,
                                               const short* __restrict__ w2p,
                                               const float* __restrict__ g1,
                                               const float* __restrict__ b1,
                                               const float* __restrict__ stats1,
                                               float* __restrict__ stats2,
                                               short* __restrict__ h2p) {
    __shared__ short wbuf[4][2336];
    __shared__ float sc1L[64], sh1L[64];
    __shared__ float redS[512], redQ[512];
    int t = threadIdx.x, lane = t & 63, w = t >> 6, ln = lane & 15, qq = lane >> 4;
    int g = blockIdx.x * 4 + w, b = g >> 10, m = g & 1023;
    float qx = xyz[((size_t)b * MM + m) * 3 + 0];
    float qy = xyz[((size_t)b * MM + m) * 3 + 1];
    float qz = xyz[((size_t)b * MM + m) * 3 + 2];
    short* R = wbuf[w];
    GATHER_WAVE(R)
    BN1_SCALES
    f32x4 acc1[2][4];
    L1_SWAPPED(R, acc1)
    __syncthreads();  // sc1L ready (feat already consumed into bAct)
    // h1 epilogue: BN1 + gelu, b64 writes into [sample][ch] tile (stride 72, cols < 64)
#pragma unroll
    for (int sf = 0; sf < 2; ++sf)
#pragma unroll
        for (int nf = 0; nf < 4; ++nf) {
            int c0 = nf * 16 + qq * 4;
            f32x4 sc = *(const f32x4*)(sc1L + c0);
            f32x4 sh = *(const f32x4*)(sh1L + c0);
            short4v sv;
#pragma unroll
            for (int jj = 0; jj < 4; ++jj)
                sv[jj] = f2b(gelu_t(acc1[sf][nf][jj] * sc[jj] + sh[jj]));
            *(short4v*)(R + (sf * 16 + ln) * 72 + c0) = sv;
        }
    // L2 swapped: A = w2p frags (coalesced), B = h1 tile
    short8 bh1[2][2];
#pragma unroll
    for (int sf = 0; sf < 2; ++sf)
#pragma unroll
        for (int kf = 0; kf < 2; ++kf)
            bh1[sf][kf] = *(const short8*)(R + (sf * 16 + ln) * 72 + kf * 32 + qq * 8);
    f32x4 acc2[2][8];
#pragma unroll
    for (int sf = 0; sf < 2; ++sf)
#pragma unroll
        for (int nf = 0; nf < 8; ++nf) acc2[sf][nf] = zero4();
#pragma unroll
    for (int kf = 0; kf < 2; ++kf)
#pragma unroll
        for (int nf = 0; nf < 8; ++nf) {
            short8 aW = *(const short8*)(w2p + (((kf * 8 + nf) * 64) + lane) * 8);
            acc2[0][nf] = mfma(aW, bh1[0][kf], acc2[0][nf]);
            acc2[1][nf] = mfma(aW, bh1[1][kf], acc2[1][nf]);
        }
    // packed lane-major store of pre-BN h2
    {
        short* hb2 = h2p + (size_t)g * 4096;
#pragma unroll
        for (int i = 0; i < 8; ++i) {
            int sf = i >> 2, p = i & 3;
            *(short8*)(hb2 + (i * 64 + lane) * 8) = pack8(acc2[sf][2 * p], acc2[sf][2 * p + 1]);
        }
    }
    // stats2
#pragma unroll
    for (int nf = 0; nf < 8; ++nf) {
        f32x4 s, q;
#pragma unroll
        for (int jj = 0; jj < 4; ++jj) {
            float a0 = acc2[0][nf][jj], a1 = acc2[1][nf][jj];
            s[jj] = a0 + a1; q[jj] = a0 * a0 + a1 * a1;
        }
#pragma unroll
        for (int d = 1; d < 16; d <<= 1) {
#pragma unroll
            for (int jj = 0; jj < 4; ++jj) {
                s[jj] += __shfl_xor(s[jj], d);
                q[jj] += __shfl_xor(q[jj], d);
            }
        }
        if (ln == 0) {
            *(f32x4*)(redS + w * 128 + nf * 16 + qq * 4) = s;
            *(f32x4*)(redQ + w * 128 + nf * 16 + qq * 4) = q;
        }
    }
    __syncthreads();
    if (t < 128) {
        float s = redS[t] + redS[128 + t] + redS[256 + t] + redS[384 + t];
        float q = redQ[t] + redQ[128 + t] + redQ[256 + t] + redQ[384 + t];
        float* st = stats2 + (blockIdx.x & 7) * 256;
        atomicAdd(&st[t], s);
        atomicAdd(&st[128 + t], q);
    }
}

// ---------------- k3: packed pre-h2 read -> BN2+gelu -> LDS -> L3 (w3p) + max + fused stats3 ----------------
__global__ __launch_bounds__(256, 4) void k3(const short* __restrict__ h2p,
                                             const short* __restrict__ w3p,
                                             const float* __restrict__ g2,
                                             const float* __restrict__ b2,
                                             const float* __restrict__ stats2,
                                             float* __restrict__ stats3,
                                             float* __restrict__ out) {
    __shared__ short wbuf[4][4352];   // per-wave [32 sample][136] h2 tile
    __shared__ float sc2L[128], sh2L[128];
    __shared__ float mxS[4][256];     // per-wave channel max (for fused stats3)
    int t = threadIdx.x, lane = t & 63, w = t >> 6, ln = lane & 15, qq = lane >> 4;
    int g = blockIdx.x * 4 + w;
    const short* hb = h2p + (size_t)g * 4096;
    short8 hv[8];
#pragma unroll
    for (int i = 0; i < 8; ++i) hv[i] = *(const short8*)(hb + (i * 64 + lane) * 8);
    if (t < 128) {
        float s = 0.f, sq = 0.f;
#pragma unroll
        for (int r = 0; r < 8; ++r) { s += stats2[r * 256 + t]; sq += stats2[r * 256 + 128 + t]; }
        float mu = s * (1.f / S1f);
        float var = sq * (1.f / S1f) - mu * mu;
        float rs = rsqrtf(var + EPSV);
        float sc = g2[t] * rs;
        sc2L[t] = sc;
        sh2L[t] = b2[t] - mu * sc;
    }
    __syncthreads();  // scales ready
    short* R = wbuf[w];
#pragma unroll
    for (int i = 0; i < 8; ++i) {
        int sf = i >> 2, p = i & 3;
#pragma unroll
        for (int hh = 0; hh < 2; ++hh) {
            int c0 = (2 * p + hh) * 16 + qq * 4;
            f32x4 sc = *(const f32x4*)(sc2L + c0);
            f32x4 sh = *(const f32x4*)(sh2L + c0);
            short4v sv;
#pragma unroll
            for (int jj = 0; jj < 4; ++jj)
                sv[jj] = f2b(gelu_t(b2f(hv[i][hh * 4 + jj]) * sc[jj] + sh[jj]));
            *(short4v*)(R + (sf * 16 + ln) * 136 + c0) = sv;
        }
    }
    short8 b3[2][4];
#pragma unroll
    for (int sf = 0; sf < 2; ++sf)
#pragma unroll
        for (int kf = 0; kf < 4; ++kf)
            b3[sf][kf] = *(const short8*)(R + (sf * 16 + ln) * 136 + kf * 32 + qq * 8);
#pragma unroll
    for (int nc = 0; nc < 4; ++nc) {
        f32x4 acc3[2][4];
#pragma unroll
        for (int sf = 0; sf < 2; ++sf)
#pragma unroll
            for (int nf = 0; nf < 4; ++nf) acc3[sf][nf] = zero4();
#pragma unroll
        for (int kf = 0; kf < 4; ++kf)
#pragma unroll
            for (int nf = 0; nf < 4; ++nf) {
                short8 aW = *(const short8*)(w3p + (((nc * 4 + kf) * 4 + nf) * 64 + lane) * 8);
                acc3[0][nf] = mfma(aW, b3[0][kf], acc3[0][nf]);
                acc3[1][nf] = mfma(aW, b3[1][kf], acc3[1][nf]);
            }
#pragma unroll
        for (int nf = 0; nf < 4; ++nf) {
            f32x4 v;
#pragma unroll
            for (int jj = 0; jj < 4; ++jj) v[jj] = fmaxf(acc3[0][nf][jj], acc3[1][nf][jj]);
#pragma unroll
            for (int d = 1; d < 16; d <<= 1) {
#pragma unroll
                for (int jj = 0; jj < 4; ++jj) v[jj] = fmaxf(v[jj], __shfl_xor(v[jj], d));
            }
            if (ln == 0) {
                *(f32x4*)(out + (size_t)g * 256 + nc * 64 + nf * 16 + qq * 4) = v;
                *(f32x4*)(&mxS[w][nc * 64 + nf * 16 + qq * 4]) = v;
            }
        }
    }
    __syncthreads();  // mxS complete
    {
        float a0 = mxS[0][t], a1 = mxS[1][t], a2 = mxS[2][t], a3 = mxS[3][t];
        float s = a0 + a1 + a2 + a3;
        float q = a0 * a0 + a1 * a1 + a2 * a2 + a3 * a3;
        float* st = stats3 + (blockIdx.x & 7) * 512;
        atomicAdd(&st[t], s);
        atomicAdd(&st[256 + t], q);
    }
}

// ---------------- final BN + exact GELU (reads 8-replicated stats3) ----------------
__global__ __launch_bounds__(256) void k_bn3(float* __restrict__ out,
                                             const float* __restrict__ stats3,
                                             const float* __restrict__ gl,
                                             const float* __restrict__ bl) {
    int i = blockIdx.x * 256 + threadIdx.x;
    int o = i & 255;
    float s = 0.f, q = 0.f;
#pragma unroll
    for (int r = 0; r < 8; ++r) { s += stats3[r * 512 + o]; q += stats3[r * 512 + 256 + o]; }
    float mu = s * (1.f / S3f);
    float var = q * (1.f / S3f) - mu * mu;
    float rs = rsqrtf(var + EPSV);
    float x = out[i];
    out[i] = gelu_e((x - mu) * rs * gl[o] + bl[o]);
}

extern "C" void kernel_launch(void* const* d_in, const int* in_sizes, int n_in,
                              void* d_out, int out_size, void* d_ws, size_t ws_size,
                              hipStream_t stream) {
    const float* src_x   = (const float*)d_in[0];
    const float* src_xyz = (const float*)d_in[1];
    const float* xyz     = (const float*)d_in[2];
    const float* w1      = (const float*)d_in[3];
    const float* g1      = (const float*)d_in[4];
    const float* b1      = (const float*)d_in[5];
    const float* w2      = (const float*)d_in[6];
    const float* g2      = (const float*)d_in[7];
    const float* b2      = (const float*)d_in[8];
    const float* w3      = (const float*)d_in[9];
    const float* gl      = (const float*)d_in[10];
    const float* bl      = (const float*)d_in[11];
    float* out = (float*)d_out;

    int* gidx = (int*)d_ws;                              // 2 MB
    float* statsF = (float*)(gidx + BB * MM * KNN);
    float* stats1 = statsF;          // 8 x (64 sum | 64 sq)   = 1024
    float* stats2 = statsF + 1024;   // 8 x (128 sum | 128 sq) = 2048
    float* stats3 = statsF + 3072;   // 8 x (256 sum | 256 sq) = 4096
    short* wb = (short*)(statsF + 7168);
    short* w1p = wb;                 // [12][64][8] lane-major frag pack (12 KB)
    short* w2p = wb + 6144;          // [16][64][8] (16 KB)
    short* w3p = wb + 14336;         // [64][64][8] (64 KB)
    short* src_xb = wb + 47104;      // [B][N][64] bf16
    // packed pre-BN h2: 128 MB at 16 MB offset (ws >= 151 MB proven in rounds 9-14)
    short* h2p = (short*)((char*)d_ws + (size_t)(16u << 20));

    hipMemsetAsync(statsF, 0, 7168 * sizeof(float), stream);
    k_prep<<<2232, 256, 0, stream>>>(src_x, w1, w2, w3, src_xb, w1p, w2p, w3p);
    k_ballquery<<<(BB * MM) / 16, 256, 0, stream>>>(src_xyz, xyz, gidx);
    k_s1<<<(BB * MM) / 4, 256, 0, stream>>>(gidx, src_xyz, xyz, src_xb, w1p, stats1);
    k_s2<<<(BB * MM) / 4, 256, 0, stream>>>(gidx, src_xyz, xyz, src_xb, w1p, w2p, g1, b1,
                                            stats1, stats2, h2p);
    k3<<<(BB * MM) / 4, 256, 0, stream>>>(h2p, w3p, g2, b2, stats2, stats3, out);
    k_bn3<<<BB * MM, 256, 0, stream>>>(out, stats3, gl, bl);
}

// Round 17
// 229.137 us; speedup vs baseline: 1.3627x; 1.1350x over previous
//
#include <hip/hip_runtime.h>
#include <math.h>

#define BB 16
#define NN 4096
#define MM 1024
#define KNN 32
#define R2 0.04f
#define EPSV 1e-5f
#define S1f ((float)(BB * MM * KNN))
#define S3f ((float)(BB * MM))

typedef __attribute__((ext_vector_type(8))) short short8;
typedef __attribute__((ext_vector_type(4))) short short4v;
typedef __attribute__((ext_vector_type(4))) float f32x4;

__device__ __forceinline__ short f2b(float x) {
    union { float f; unsigned u; } v; v.f = x;
    unsigned r = v.u + 0x7fffu + ((v.u >> 16) & 1u);
    return (short)(r >> 16);
}
__device__ __forceinline__ float b2f(short s) {
    union { unsigned u; float f; } v; v.u = ((unsigned)(unsigned short)s) << 16;
    return v.f;
}
// fast tanh-gelu: 0.5x(1+tanh u) == x * (1 - 1/(e^{2u}+1))
__device__ __forceinline__ float gelu_t(float x) {
    float u = 0.7978845608f * x * (1.f + 0.044715f * x * x);
    float e = __expf(2.f * u);
    float r = __builtin_amdgcn_rcpf(e + 1.f);
    return x - x * r;
}
__device__ __forceinline__ float gelu_e(float x) {  // exact (final output)
    return 0.5f * x * (1.f + erff(x * 0.7071067811865475f));
}
__device__ __forceinline__ f32x4 zero4() { f32x4 z = {0.f, 0.f, 0.f, 0.f}; return z; }
__device__ __forceinline__ f32x4 mfma(short8 a, short8 b, f32x4 c) {
    return __builtin_amdgcn_mfma_f32_16x16x32_bf16(a, b, c, 0, 0, 0);
}
__device__ __forceinline__ short8 pack8(f32x4 a, f32x4 b) {
    short8 r;
    r[0] = f2b(a[0]); r[1] = f2b(a[1]); r[2] = f2b(a[2]); r[3] = f2b(a[3]);
    r[4] = f2b(b[0]); r[5] = f2b(b[1]); r[6] = f2b(b[2]); r[7] = f2b(b[3]);
    return r;
}

// ---------------- ball query: one query per wave ----------------
__global__ __launch_bounds__(256) void k_ballquery(const float* __restrict__ src_xyz,
                                                   const float* __restrict__ xyz,
                                                   int* __restrict__ gidx) {
    __shared__ float sx[NN], sy[NN], sz[NN];
    int t = threadIdx.x;
    int lane = t & 63, w = t >> 6;
    int q0 = blockIdx.x * 16;
    int b = q0 >> 10;
    const float* sp = src_xyz + (size_t)b * NN * 3;
    for (int i = t; i < NN * 3; i += 256) {
        float v = sp[i];
        int j = i / 3, d = i - j * 3;
        if (d == 0) sx[j] = v;
        else if (d == 1) sy[j] = v;
        else sz[j] = v;
    }
    __syncthreads();
#pragma unroll
    for (int qi = 0; qi < 4; ++qi) {
        int q = q0 + w * 4 + qi;
        int m = q & 1023;
        float qx = xyz[((size_t)b * MM + m) * 3 + 0];
        float qy = xyz[((size_t)b * MM + m) * 3 + 1];
        float qz = xyz[((size_t)b * MM + m) * 3 + 2];
        int* outp = gidx + (size_t)q * KNN;
        int cnt = 0, firstj = -1;
        for (int j0 = 0; j0 < NN && cnt < KNN; j0 += 64) {
            int j = j0 + lane;
            float dx = qx - sx[j];
            float dy = qy - sy[j];
            float dz = qz - sz[j];
            bool hit = (dx * dx + dy * dy + dz * dz) <= R2;
            unsigned long long mask = __ballot(hit);
            if (hit) {
                int rank = cnt + __popcll(mask & ((1ull << lane) - 1ull));
                if (rank < KNN) outp[rank] = j;
            }
            if (firstj < 0 && mask != 0ull) firstj = j0 + __ffsll((long long)mask) - 1;
            cnt += __popcll(mask);
        }
        if (cnt < KNN) {
            int fj = (firstj < 0) ? 0 : firstj;
            for (int k = cnt + lane; k < KNN; k += 64) outp[k] = fj;
        }
    }
}

// ---------------- prep: src_x -> bf16; w1/w2/w3 -> lane-major MFMA fragment packs ----------------
// wp[(frag)*512 + lane*8 + e] with row n = nf*16+(lane&15), col k = kf*32+(lane>>4)*8+e.
// Same per-lane data serves W as A-operand (row n) or B-operand (col n of W^T).
__global__ __launch_bounds__(256) void k_prep(const float* __restrict__ src_x,
                                              const float* __restrict__ w1,
                                              const float* __restrict__ w2,
                                              const float* __restrict__ w3,
                                              short* __restrict__ src_xb,
                                              short* __restrict__ w1p,
                                              short* __restrict__ w2p,
                                              short* __restrict__ w3p) {
    int i = blockIdx.x * 256 + threadIdx.x;
    if (i < 524288) {  // BB*NN*64/8
        const f32x4* p = (const f32x4*)(src_x + (size_t)i * 8);
        *(short8*)(src_xb + (size_t)i * 8) = pack8(p[0], p[1]);
    } else {
        int j = i - 524288;
        if (j < 6144) {            // w1p: 12 frags (kf 0..2, nf 0..3), reordered K
            int e = j & 7, lane = (j >> 3) & 63, idx = j >> 9;
            int kf = idx >> 2, nf = idx & 3;
            int ln = lane & 15, qq = lane >> 4;
            int n = nf * 16 + ln, k = kf * 32 + qq * 8 + e;
            float v = 0.f;
            if (k < 64) v = w1[n * 67 + 3 + k];
            else if (k < 67) v = w1[n * 67 + (k - 64)];
            w1p[j] = f2b(v);
        } else if (j < 14336) {    // w2p: 16 frags (kf 0..1, nf 0..7)
            int j2 = j - 6144;
            int e = j2 & 7, lane = (j2 >> 3) & 63, idx = j2 >> 9;
            int kf = idx >> 3, nf = idx & 7;
            int ln = lane & 15, qq = lane >> 4;
            w2p[j2] = f2b(w2[(nf * 16 + ln) * 64 + kf * 32 + qq * 8 + e]);
        } else if (j < 47104) {    // w3p: 64 frags (nc 0..3, kf 0..3, nf 0..3)
            int j2 = j - 14336;
            int e = j2 & 7, lane = (j2 >> 3) & 63, idx = j2 >> 9;
            int nf = idx & 3, kf = (idx >> 2) & 3, nc = idx >> 4;
            int ln = lane & 15, qq = lane >> 4;
            w3p[j2] = f2b(w3[(size_t)(nc * 64 + nf * 16 + ln) * 128 + kf * 32 + qq * 8 + e]);
        }
    }
}

// Per-wave gather into wave-private region R (feat rows stride 72, 16B-aligned).
#define GATHER_WAVE(R)                                                                  \
    {                                                                                   \
        if (lane < 8) { short4v z4 = {0, 0, 0, 0};                                      \
            *(short4v*)((R) + 2304 + lane * 4) = z4; }                                  \
        int r = lane >> 1, hf = lane & 1;                                               \
        int jdx = gidx[(size_t)g * KNN + r];                                            \
        const short8* sp = (const short8*)(src_xb + ((size_t)b * NN + jdx) * 64 + hf * 32); \
        *(short8*)((R) + r * 72 + hf * 32) = sp[0];                                     \
        *(short8*)((R) + r * 72 + hf * 32 + 8) = sp[1];                                 \
        *(short8*)((R) + r * 72 + hf * 32 + 16) = sp[2];                                \
        *(short8*)((R) + r * 72 + hf * 32 + 24) = sp[3];                                \
        if (hf == 0) {                                                                  \
            const float* spp = src_xyz + ((size_t)b * NN + jdx) * 3;                    \
            short4v z;                                                                  \
            z[0] = f2b(spp[0] - qx); z[1] = f2b(spp[1] - qy);                           \
            z[2] = f2b(spp[2] - qz); z[3] = 0;                                          \
            *(short4v*)((R) + r * 72 + 64) = z;                                         \
            short4v z0 = {0, 0, 0, 0};                                                  \
            *(short4v*)((R) + r * 72 + 68) = z0;                                        \
        }                                                                               \
    }

// Build BN1 scale/shift into sc1L/sh1L (threads t<64)
#define BN1_SCALES                                                                      \
    if (t < 64) {                                                                       \
        float s = 0.f, sq = 0.f;                                                        \
        _Pragma("unroll")                                                               \
        for (int r = 0; r < 8; ++r) { s += stats1[r * 128 + t]; sq += stats1[r * 128 + 64 + t]; } \
        float mu = s * (1.f / S1f);                                                     \
        float var = sq * (1.f / S1f) - mu * mu;                                         \
        float rs = rsqrtf(var + EPSV);                                                  \
        float sc = g1[t] * rs;                                                          \
        sc1L[t] = sc;                                                                   \
        sh1L[t] = b1[t] - mu * sc;                                                      \
    }

// L1 swapped (W1 = A): acc1[sf][nf]: D rows=ch nf*16+qq*4+jj, cols=sample sf*16+ln
// (used by s2 which needs channel-grouped acc for vectorized h1 epilogue)
#define L1_SWAPPED(R, acc1)                                                             \
    short8 bAct[2][3];                                                                  \
    _Pragma("unroll")                                                                   \
    for (int sf = 0; sf < 2; ++sf)                                                      \
        _Pragma("unroll")                                                               \
        for (int kf = 0; kf < 3; ++kf)                                                  \
            bAct[sf][kf] = *(const short8*)((R) + (sf * 16 + ln) * 72 + kf * 32 + qq * 8); \
    _Pragma("unroll")                                                                   \
    for (int sf = 0; sf < 2; ++sf)                                                      \
        _Pragma("unroll")                                                               \
        for (int nf = 0; nf < 4; ++nf) acc1[sf][nf] = zero4();                          \
    _Pragma("unroll")                                                                   \
    for (int kf = 0; kf < 3; ++kf)                                                      \
        _Pragma("unroll")                                                               \
        for (int nf = 0; nf < 4; ++nf) {                                                \
            short8 aW = *(const short8*)(w1p + (((kf * 4 + nf) * 64) + lane) * 8);      \
            acc1[0][nf] = mfma(aW, bAct[0][kf], acc1[0][nf]);                           \
            acc1[1][nf] = mfma(aW, bAct[1][kf], acc1[1][nf]);                           \
        }

// ---------------- s1: gather + L1 (UNSWAPPED: samples in D-rows) + cheap stats1 ----------------
__global__ __launch_bounds__(256, 6) void k_s1(const int* __restrict__ gidx,
                                               const float* __restrict__ src_xyz,
                                               const float* __restrict__ xyz,
                                               const short* __restrict__ src_xb,
                                               const short* __restrict__ w1p,
                                               float* __restrict__ stats1) {
    __shared__ short wbuf[4][2336];
    __shared__ float redS[256], redQ[256];
    int t = threadIdx.x, lane = t & 63, w = t >> 6, ln = lane & 15, qq = lane >> 4;
    int g = blockIdx.x * 4 + w, b = g >> 10, m = g & 1023;
    float qx = xyz[((size_t)b * MM + m) * 3 + 0];
    float qy = xyz[((size_t)b * MM + m) * 3 + 1];
    float qz = xyz[((size_t)b * MM + m) * 3 + 2];
    short* R = wbuf[w];
    GATHER_WAVE(R)
    // unswapped: A = feat rows (samples), B = w1p; D rows = sample sf*16+qq*4+jj, col = ch nf*16+ln
    short8 aAct[2][3];
#pragma unroll
    for (int sf = 0; sf < 2; ++sf)
#pragma unroll
        for (int kf = 0; kf < 3; ++kf)
            aAct[sf][kf] = *(const short8*)(R + (sf * 16 + ln) * 72 + kf * 32 + qq * 8);
    f32x4 acc1[2][4];
#pragma unroll
    for (int sf = 0; sf < 2; ++sf)
#pragma unroll
        for (int nf = 0; nf < 4; ++nf) acc1[sf][nf] = zero4();
#pragma unroll
    for (int kf = 0; kf < 3; ++kf)
#pragma unroll
        for (int nf = 0; nf < 4; ++nf) {
            short8 bW = *(const short8*)(w1p + (((kf * 4 + nf) * 64) + lane) * 8);
            acc1[0][nf] = mfma(aAct[0][kf], bW, acc1[0][nf]);
            acc1[1][nf] = mfma(aAct[1][kf], bW, acc1[1][nf]);
        }
    // stats1: sum over samples = jj-tree + sf + 2-step qq shuffle; lane qq==0 holds ch nf*16+ln
#pragma unroll
    for (int nf = 0; nf < 4; ++nf) {
        f32x4 sv, qv;
#pragma unroll
        for (int jj = 0; jj < 4; ++jj) {
            float a0 = acc1[0][nf][jj], a1 = acc1[1][nf][jj];
            sv[jj] = a0 + a1; qv[jj] = a0 * a0 + a1 * a1;
        }
        float s = (sv[0] + sv[1]) + (sv[2] + sv[3]);
        float q = (qv[0] + qv[1]) + (qv[2] + qv[3]);
        s += __shfl_xor(s, 16); s += __shfl_xor(s, 32);
        q += __shfl_xor(q, 16); q += __shfl_xor(q, 32);
        if (qq == 0) { redS[w * 64 + nf * 16 + ln] = s; redQ[w * 64 + nf * 16 + ln] = q; }
    }
    __syncthreads();
    if (t < 64) {
        float s = redS[t] + redS[64 + t] + redS[128 + t] + redS[192 + t];
        float q = redQ[t] + redQ[64 + t] + redQ[128 + t] + redQ[192 + t];
        float* st = stats1 + (blockIdx.x & 7) * 128;
        atomicAdd(&st[t], s);
        atomicAdd(&st[64 + t], q);
    }
}

// ---------------- s2: gather + L1 (swapped) + BN1/gelu + L2 (swapped) + stats2 + h2p store ----------------
__global__ __launch_bounds__(256, 4) void k_s2(const int* __restrict__ gidx,
                                               const float* __restrict__ src_xyz,
                                               const float* __restrict__ xyz,
                                               const short* __restrict__ src_xb,
                                               const short* __restrict__ w1p,
                                               const short* __restrict__ w2p,
                                               const float* __restrict__ g1,
                                               const float* __restrict__ b1,
                                               const float* __restrict__ stats1,
                                               float* __restrict__ stats2,
                                               short* __restrict__ h2p) {
    __shared__ short wbuf[4][2336];
    __shared__ float sc1L[64], sh1L[64];
    __shared__ float redS[512], redQ[512];
    int t = threadIdx.x, lane = t & 63, w = t >> 6, ln = lane & 15, qq = lane >> 4;
    int g = blockIdx.x * 4 + w, b = g >> 10, m = g & 1023;
    float qx = xyz[((size_t)b * MM + m) * 3 + 0];
    float qy = xyz[((size_t)b * MM + m) * 3 + 1];
    float qz = xyz[((size_t)b * MM + m) * 3 + 2];
    short* R = wbuf[w];
    GATHER_WAVE(R)
    BN1_SCALES
    f32x4 acc1[2][4];
    L1_SWAPPED(R, acc1)
    __syncthreads();  // sc1L ready (feat already consumed into bAct)
    // h1 epilogue: BN1 + gelu, b64 writes into [sample][ch] tile (stride 72, cols < 64)
#pragma unroll
    for (int sf = 0; sf < 2; ++sf)
#pragma unroll
        for (int nf = 0; nf < 4; ++nf) {
            int c0 = nf * 16 + qq * 4;
            f32x4 sc = *(const f32x4*)(sc1L + c0);
            f32x4 sh = *(const f32x4*)(sh1L + c0);
            short4v sv;
#pragma unroll
            for (int jj = 0; jj < 4; ++jj)
                sv[jj] = f2b(gelu_t(acc1[sf][nf][jj] * sc[jj] + sh[jj]));
            *(short4v*)(R + (sf * 16 + ln) * 72 + c0) = sv;
        }
    // L2 swapped: A = w2p frags (coalesced), B = h1 tile
    short8 bh1[2][2];
#pragma unroll
    for (int sf = 0; sf < 2; ++sf)
#pragma unroll
        for (int kf = 0; kf < 2; ++kf)
            bh1[sf][kf] = *(const short8*)(R + (sf * 16 + ln) * 72 + kf * 32 + qq * 8);
    f32x4 acc2[2][8];
#pragma unroll
    for (int sf = 0; sf < 2; ++sf)
#pragma unroll
        for (int nf = 0; nf < 8; ++nf) acc2[sf][nf] = zero4();
#pragma unroll
    for (int kf = 0; kf < 2; ++kf)
#pragma unroll
        for (int nf = 0; nf < 8; ++nf) {
            short8 aW = *(const short8*)(w2p + (((kf * 8 + nf) * 64) + lane) * 8);
            acc2[0][nf] = mfma(aW, bh1[0][kf], acc2[0][nf]);
            acc2[1][nf] = mfma(aW, bh1[1][kf], acc2[1][nf]);
        }
    // packed lane-major store of pre-BN h2
    {
        short* hb2 = h2p + (size_t)g * 4096;
#pragma unroll
        for (int i = 0; i < 8; ++i) {
            int sf = i >> 2, p = i & 3;
            *(short8*)(hb2 + (i * 64 + lane) * 8) = pack8(acc2[sf][2 * p], acc2[sf][2 * p + 1]);
        }
    }
    // stats2
#pragma unroll
    for (int nf = 0; nf < 8; ++nf) {
        f32x4 s, q;
#pragma unroll
        for (int jj = 0; jj < 4; ++jj) {
            float a0 = acc2[0][nf][jj], a1 = acc2[1][nf][jj];
            s[jj] = a0 + a1; q[jj] = a0 * a0 + a1 * a1;
        }
#pragma unroll
        for (int d = 1; d < 16; d <<= 1) {
#pragma unroll
            for (int jj = 0; jj < 4; ++jj) {
                s[jj] += __shfl_xor(s[jj], d);
                q[jj] += __shfl_xor(q[jj], d);
            }
        }
        if (ln == 0) {
            *(f32x4*)(redS + w * 128 + nf * 16 + qq * 4) = s;
            *(f32x4*)(redQ + w * 128 + nf * 16 + qq * 4) = q;
        }
    }
    __syncthreads();
    if (t < 128) {
        float s = redS[t] + redS[128 + t] + redS[256 + t] + redS[384 + t];
        float q = redQ[t] + redQ[128 + t] + redQ[256 + t] + redQ[384 + t];
        float* st = stats2 + (blockIdx.x & 7) * 256;
        atomicAdd(&st[t], s);
        atomicAdd(&st[128 + t], q);
    }
}

// ---------------- k3: packed pre-h2 read -> BN2+gelu -> LDS -> L3 (UNSWAPPED) + cheap max + fused stats3 ----------------
__global__ __launch_bounds__(256, 4) void k3(const short* __restrict__ h2p,
                                             const short* __restrict__ w3p,
                                             const float* __restrict__ g2,
                                             const float* __restrict__ b2,
                                             const float* __restrict__ stats2,
                                             float* __restrict__ stats3,
                                             float* __restrict__ out) {
    __shared__ short wbuf[4][4352];   // per-wave [32 sample][136] h2 tile
    __shared__ float sc2L[128], sh2L[128];
    __shared__ float mxS[4][256];     // per-wave channel max (for fused stats3)
    int t = threadIdx.x, lane = t & 63, w = t >> 6, ln = lane & 15, qq = lane >> 4;
    int g = blockIdx.x * 4 + w;
    const short* hb = h2p + (size_t)g * 4096;
    short8 hv[8];
#pragma unroll
    for (int i = 0; i < 8; ++i) hv[i] = *(const short8*)(hb + (i * 64 + lane) * 8);
    if (t < 128) {
        float s = 0.f, sq = 0.f;
#pragma unroll
        for (int r = 0; r < 8; ++r) { s += stats2[r * 256 + t]; sq += stats2[r * 256 + 128 + t]; }
        float mu = s * (1.f / S1f);
        float var = sq * (1.f / S1f) - mu * mu;
        float rs = rsqrtf(var + EPSV);
        float sc = g2[t] * rs;
        sc2L[t] = sc;
        sh2L[t] = b2[t] - mu * sc;
    }
    __syncthreads();  // scales ready
    short* R = wbuf[w];
#pragma unroll
    for (int i = 0; i < 8; ++i) {
        int sf = i >> 2, p = i & 3;
#pragma unroll
        for (int hh = 0; hh < 2; ++hh) {
            int c0 = (2 * p + hh) * 16 + qq * 4;
            f32x4 sc = *(const f32x4*)(sc2L + c0);
            f32x4 sh = *(const f32x4*)(sh2L + c0);
            short4v sv;
#pragma unroll
            for (int jj = 0; jj < 4; ++jj)
                sv[jj] = f2b(gelu_t(b2f(hv[i][hh * 4 + jj]) * sc[jj] + sh[jj]));
            *(short4v*)(R + (sf * 16 + ln) * 136 + c0) = sv;
        }
    }
    // L3 unswapped: A = h2 rows (samples) from tile, B = w3p frags.
    // D rows = sample sf*16+qq*4+jj, cols = ch nc*64+nf*16+ln
    short8 a3[2][4];
#pragma unroll
    for (int sf = 0; sf < 2; ++sf)
#pragma unroll
        for (int kf = 0; kf < 4; ++kf)
            a3[sf][kf] = *(const short8*)(R + (sf * 16 + ln) * 136 + kf * 32 + qq * 8);
#pragma unroll
    for (int nc = 0; nc < 4; ++nc) {
        f32x4 acc3[2][4];
#pragma unroll
        for (int sf = 0; sf < 2; ++sf)
#pragma unroll
            for (int nf = 0; nf < 4; ++nf) acc3[sf][nf] = zero4();
#pragma unroll
        for (int kf = 0; kf < 4; ++kf)
#pragma unroll
            for (int nf = 0; nf < 4; ++nf) {
                short8 bW = *(const short8*)(w3p + (((nc * 4 + kf) * 4 + nf) * 64 + lane) * 8);
                acc3[0][nf] = mfma(a3[0][kf], bW, acc3[0][nf]);
                acc3[1][nf] = mfma(a3[1][kf], bW, acc3[1][nf]);
            }
        // max over samples: jj-tree (in-reg) + sf + 2-step qq shuffle; qq==0 holds ch nf*16+ln
#pragma unroll
        for (int nf = 0; nf < 4; ++nf) {
            f32x4 v0 = acc3[0][nf], v1 = acc3[1][nf];
            float m0 = fmaxf(fmaxf(v0[0], v0[1]), fmaxf(v0[2], v0[3]));
            float m1 = fmaxf(fmaxf(v1[0], v1[1]), fmaxf(v1[2], v1[3]));
            float mm = fmaxf(m0, m1);
            mm = fmaxf(mm, __shfl_xor(mm, 16));
            mm = fmaxf(mm, __shfl_xor(mm, 32));
            if (qq == 0) {
                out[(size_t)g * 256 + nc * 64 + nf * 16 + ln] = mm;
                mxS[w][nc * 64 + nf * 16 + ln] = mm;
            }
        }
    }
    __syncthreads();  // mxS complete
    {
        float a0 = mxS[0][t], a1 = mxS[1][t], a2 = mxS[2][t], a3v = mxS[3][t];
        float s = a0 + a1 + a2 + a3v;
        float q = a0 * a0 + a1 * a1 + a2 * a2 + a3v * a3v;
        float* st = stats3 + (blockIdx.x & 7) * 512;
        atomicAdd(&st[t], s);
        atomicAdd(&st[256 + t], q);
    }
}

// ---------------- final BN + exact GELU (reads 8-replicated stats3) ----------------
__global__ __launch_bounds__(256) void k_bn3(float* __restrict__ out,
                                             const float* __restrict__ stats3,
                                             const float* __restrict__ gl,
                                             const float* __restrict__ bl) {
    int i = blockIdx.x * 256 + threadIdx.x;
    int o = i & 255;
    float s = 0.f, q = 0.f;
#pragma unroll
    for (int r = 0; r < 8; ++r) { s += stats3[r * 512 + o]; q += stats3[r * 512 + 256 + o]; }
    float mu = s * (1.f / S3f);
    float var = q * (1.f / S3f) - mu * mu;
    float rs = rsqrtf(var + EPSV);
    float x = out[i];
    out[i] = gelu_e((x - mu) * rs * gl[o] + bl[o]);
}

extern "C" void kernel_launch(void* const* d_in, const int* in_sizes, int n_in,
                              void* d_out, int out_size, void* d_ws, size_t ws_size,
                              hipStream_t stream) {
    const float* src_x   = (const float*)d_in[0];
    const float* src_xyz = (const float*)d_in[1];
    const float* xyz     = (const float*)d_in[2];
    const float* w1      = (const float*)d_in[3];
    const float* g1      = (const float*)d_in[4];
    const float* b1      = (const float*)d_in[5];
    const float* w2      = (const float*)d_in[6];
    const float* g2      = (const float*)d_in[7];
    const float* b2      = (const float*)d_in[8];
    const float* w3      = (const float*)d_in[9];
    const float* gl      = (const float*)d_in[10];
    const float* bl      = (const float*)d_in[11];
    float* out = (float*)d_out;

    int* gidx = (int*)d_ws;                              // 2 MB
    float* statsF = (float*)(gidx + BB * MM * KNN);
    float* stats1 = statsF;          // 8 x (64 sum | 64 sq)   = 1024
    float* stats2 = statsF + 1024;   // 8 x (128 sum | 128 sq) = 2048
    float* stats3 = statsF + 3072;   // 8 x (256 sum | 256 sq) = 4096
    short* wb = (short*)(statsF + 7168);
    short* w1p = wb;                 // [12][64][8] lane-major frag pack (12 KB)
    short* w2p = wb + 6144;          // [16][64][8] (16 KB)
    short* w3p = wb + 14336;         // [64][64][8] (64 KB)
    short* src_xb = wb + 47104;      // [B][N][64] bf16
    // packed pre-BN h2: 128 MB at 16 MB offset (ws >= 151 MB proven in rounds 9-16)
    short* h2p = (short*)((char*)d_ws + (size_t)(16u << 20));

    hipMemsetAsync(statsF, 0, 7168 * sizeof(float), stream);
    k_prep<<<2232, 256, 0, stream>>>(src_x, w1, w2, w3, src_xb, w1p, w2p, w3p);
    k_ballquery<<<(BB * MM) / 16, 256, 0, stream>>>(src_xyz, xyz, gidx);
    k_s1<<<(BB * MM) / 4, 256, 0, stream>>>(gidx, src_xyz, xyz, src_xb, w1p, stats1);
    k_s2<<<(BB * MM) / 4, 256, 0, stream>>>(gidx, src_xyz, xyz, src_xb, w1p, w2p, g1, b1,
                                            stats1, stats2, h2p);
    k3<<<(BB * MM) / 4, 256, 0, stream>>>(h2p, w3p, g2, b2, stats2, stats3, out);
    k_bn3<<<BB * MM, 256, 0, stream>>>(out, stats3, gl, bl);
}